// Round 1
// 524.275 us; speedup vs baseline: 1.0908x; 1.0908x over previous
//
#include <hip/hip_runtime.h>
#include <hip/hip_bf16.h>
#include <stdint.h>

// ---------------------------------------------------------------------------
// TernaryLinear: out[b,s,o] = t * sum_i x[b,s,i] * q[o,i]
//   q = ternary(weight) in {-1,0,+1}; t = clip(round(1/(mean|W|+eps)),-1,1)
// R2: 256x256 tile, 8-wave phase-split schedule with counted vmcnt (T3+T4),
//     setprio around MFMA clusters (T5), XCD swizzle (T1), 2-bit-mixed XOR
//     LDS swizzle (T2). BK=32 so the double-buffered tile fits 64KB static
//     LDS. Never drains vmcnt to 0 inside the K-loop.
// ---------------------------------------------------------------------------

typedef __bf16 bf16x8 __attribute__((ext_vector_type(8)));
typedef float  f32x4  __attribute__((ext_vector_type(4)));

#define EPS 1e-7f
#define NPART 4096   // partial-sum slots (quant kernel grid size)

__device__ __forceinline__ void async_load16(const void* g, void* l) {
    __builtin_amdgcn_global_load_lds(
        (__attribute__((address_space(1))) void*)(const_cast<void*>(g)),
        (__attribute__((address_space(3))) void*)l,
        16, 0, 0);
}

__device__ __forceinline__ unsigned short f2bf_rne(float f) {
    unsigned u = __float_as_uint(f);
    unsigned r = (u + 0x7fffu + ((u >> 16) & 1u)) >> 16;
    return (unsigned short)r;
}

// Reduce NPART partials -> scalar scale t. Redundant per-wave (L2-hot 16KB).
__device__ __forceinline__ float scale_from_partials(const float* __restrict__ partials,
                                                     float invCount) {
    const int lane = threadIdx.x & 63;
    const float4* p4 = (const float4*)partials;   // NPART/4 = 1024 entries
    float s = 0.0f;
    #pragma unroll
    for (int j = 0; j < NPART / 4 / 64; ++j) {
        float4 v = p4[lane + 64 * j];
        s += v.x + v.y + v.z + v.w;
    }
    #pragma unroll
    for (int off = 32; off > 0; off >>= 1) s += __shfl_down(s, off, 64);
    s = __shfl(s, 0, 64);
    float mean = s * invCount;
    float gp = 1.0f / (mean + EPS);
    return fminf(fmaxf(rintf(gp), -1.0f), 1.0f);  // rintf = RNE = half-to-even
}

// ---- fused quantize W -> bf16 ternary + per-block |W| partial sums --------

__device__ __forceinline__ unsigned short tern_bf16(float w) {
    // +1 -> 0x3F80, -1 -> 0xBF80, 0 -> 0x0000 (exact bf16 bit patterns)
    return (w > 0.5f) ? (unsigned short)0x3F80u
         : ((w < -0.5f) ? (unsigned short)0xBF80u : (unsigned short)0u);
}

__global__ __launch_bounds__(256) void quant_w_bf16(
    const float* __restrict__ in, ushort4* __restrict__ out,
    float* __restrict__ partials, int n4)
{
    int tid = blockIdx.x * blockDim.x + threadIdx.x;
    int stride = gridDim.x * blockDim.x;
    float s = 0.0f;
    for (int i = tid; i < n4; i += stride) {
        float4 v = ((const float4*)in)[i];
        s += fabsf(v.x) + fabsf(v.y) + fabsf(v.z) + fabsf(v.w);
        ushort4 r;
        r.x = tern_bf16(v.x); r.y = tern_bf16(v.y);
        r.z = tern_bf16(v.z); r.w = tern_bf16(v.w);
        out[i] = r;
    }
    #pragma unroll
    for (int off = 32; off > 0; off >>= 1) s += __shfl_down(s, off, 64);
    __shared__ float psum[4];
    int lane = threadIdx.x & 63, wid = threadIdx.x >> 6;
    if (lane == 0) psum[wid] = s;
    __syncthreads();
    if (threadIdx.x == 0)
        partials[blockIdx.x] = psum[0] + psum[1] + psum[2] + psum[3];
}

// ---- x -> bf16 -------------------------------------------------------------

__global__ __launch_bounds__(256) void conv_x_bf16(
    const float* __restrict__ in, ushort4* __restrict__ out, int n4)
{
    int i = blockIdx.x * blockDim.x + threadIdx.x;
    if (i < n4) {
        float4 v = ((const float4*)in)[i];
        ushort4 r;
        r.x = f2bf_rne(v.x); r.y = f2bf_rne(v.y);
        r.z = f2bf_rne(v.z); r.w = f2bf_rne(v.w);
        out[i] = r;
    }
}

// ---- bf16 MFMA GEMM, 256x256 tile, phase-split counted-vmcnt pipeline -----
//
// 8 waves (2 row-halves x 4 col-quarters). Per wave: 128x64 output = 8x4
// 16x16 fragments. K-tile = 32. LDS: A/B each split in two 128-row halves;
// per half-tile (128x32 bf16 = 8KB) each of the 512 threads stages exactly
// one 16B chunk. Chunk (row, sc) holds source chunk cc = sc ^ (row&3) ^
// ((row>>2)&3)  -> conflict-free ds_read_b128 (<=2-way per 16-lane batch),
// linear global_load_lds dest (rule 21: swizzle source + read, dest linear).
//
// Schedule per K-tile t (cur = t&1):
//  P1: 12 ds_read_b128 (all A frags + all B frags) | stage tile t+1's A0,A1
//      -> buf cur^1 | BAR | lgkmcnt(0) | setprio(1) 16 MFMA (n0,n1) | BAR
//  P2: stage tile t+2's B0,B1 -> buf cur (B fully consumed at P1) | BAR |
//      setprio(1) 16 MFMA (n2,n3) | s_waitcnt vmcnt(2) | BAR
// In flight at every tile boundary: 2 loads/thread (tile t+2's B halves).
// Tail: prefetch sources clamped (re-staged bytes never read) so the vmcnt
// arithmetic stays uniform; vmcnt(0) drain after the loop so no late LDS
// write lands in a successor workgroup's LDS.

#define BM 256
#define BN 256
#define BK 32

#define GEMM_TILE(t_, CUR, NXT)                                                \
  {                                                                            \
    const int tA = ((t_) + 1 < T) ? ((t_) + 1) : (t_);                         \
    const int tB = ((t_) + 2 < T) ? ((t_) + 2) : (t_);                         \
    bf16x8 a[8], b[4];                                                         \
    _Pragma("unroll")                                                          \
    for (int mt = 0; mt < 8; ++mt)                                             \
      a[mt] = *(const bf16x8*)&As[CUR][wr][(mt * 16 + lm) * BK + slot8];       \
    _Pragma("unroll")                                                          \
    for (int nt = 0; nt < 4; ++nt)                                             \
      b[nt] = *(const bf16x8*)&Bs[CUR][wh][(wb + nt * 16 + lm) * BK + slot8];  \
    async_load16(gA + (size_t)tA * BK,        &As[NXT][0][(size_t)tid * 8]);   \
    async_load16(gA + gH1 + (size_t)tA * BK,  &As[NXT][1][(size_t)tid * 8]);   \
    __builtin_amdgcn_s_barrier();                                              \
    asm volatile("s_waitcnt lgkmcnt(0)" ::: "memory");                         \
    __builtin_amdgcn_s_setprio(1);                                             \
    _Pragma("unroll")                                                          \
    for (int mt = 0; mt < 8; ++mt) {                                           \
      acc[mt][0] = __builtin_amdgcn_mfma_f32_16x16x32_bf16(a[mt], b[0], acc[mt][0], 0, 0, 0); \
      acc[mt][1] = __builtin_amdgcn_mfma_f32_16x16x32_bf16(a[mt], b[1], acc[mt][1], 0, 0, 0); \
    }                                                                          \
    __builtin_amdgcn_s_setprio(0);                                             \
    __builtin_amdgcn_s_barrier();                                              \
    async_load16(gB + (size_t)tB * BK,        &Bs[CUR][0][(size_t)tid * 8]);   \
    async_load16(gB + gH1 + (size_t)tB * BK,  &Bs[CUR][1][(size_t)tid * 8]);   \
    __builtin_amdgcn_s_barrier();                                              \
    __builtin_amdgcn_s_setprio(1);                                             \
    _Pragma("unroll")                                                          \
    for (int mt = 0; mt < 8; ++mt) {                                           \
      acc[mt][2] = __builtin_amdgcn_mfma_f32_16x16x32_bf16(a[mt], b[2], acc[mt][2], 0, 0, 0); \
      acc[mt][3] = __builtin_amdgcn_mfma_f32_16x16x32_bf16(a[mt], b[3], acc[mt][3], 0, 0, 0); \
    }                                                                          \
    __builtin_amdgcn_s_setprio(0);                                             \
    asm volatile("s_waitcnt vmcnt(2)" ::: "memory");                           \
    __builtin_amdgcn_s_barrier();                                              \
  }

__global__ __launch_bounds__(512, 2) void gemm_bt(
    const __bf16* __restrict__ A,   // [M,K] row-major bf16
    const __bf16* __restrict__ B,   // [N,K] row-major bf16 (ternary)
    float* __restrict__ C,          // [M,N] row-major fp32
    const float* __restrict__ partials,
    int N, int K, float invCount)
{
    __shared__ __bf16 As[2][2][128 * BK];   // [dbuf][row-half] 32KB
    __shared__ __bf16 Bs[2][2][128 * BK];   // [dbuf][col-half] 32KB

    const int tid  = threadIdx.x;
    const int lane = tid & 63;
    const int wid  = tid >> 6;
    const int wr   = wid >> 2;        // A half this wave consumes (0,1)
    const int wc   = wid & 3;         // col quarter (0..3)
    const int wh   = wc >> 1;         // B half this wave consumes
    const int wb   = (wc & 1) * 64;   // row offset inside that B half
    const int lm   = lane & 15;
    const int quad = lane >> 4;

    // T1: XCD-aware swizzle of linear workgroup id (nwg % 8 == 0 here)
    const int gx  = gridDim.x;
    const int nwg = gx * gridDim.y;
    int wg = blockIdx.y * gx + blockIdx.x;
    wg = (wg & 7) * (nwg >> 3) + (wg >> 3);
    const int mBase = (wg / gx) * BM;
    const int nBase = (wg % gx) * BN;

    // staging geometry: thread stages chunk (srow, tid&3); source chunk cc
    const int srow = tid >> 2;
    const int scc  = (tid & 3) ^ (srow & 3) ^ ((srow >> 2) & 3);
    // read-side swizzled slot: slot = quad ^ (row&3) ^ ((row>>2)&3); the row
    // terms reduce to lm bits (mt*16, nt*16, wb are 0 mod 16) -> per-lane const
    const int slot8 = (quad ^ (lm & 3) ^ ((lm >> 2) & 3)) * 8;

    const __bf16* gA = A + (size_t)(mBase + srow) * K + scc * 8;
    const __bf16* gB = B + (size_t)(nBase + srow) * K + scc * 8;
    const size_t gH1 = (size_t)128 * K;   // second 128-row half

    const int T = K / BK;
    f32x4 acc[8][4] = {};

    // prologue: tile0 {B0,B1,A0,A1}, tile1 {B0,B1}; leave tile1's B in flight
    {
        const size_t k1 = (T > 1) ? BK : 0;
        async_load16(gB,            &Bs[0][0][(size_t)tid * 8]);
        async_load16(gB + gH1,      &Bs[0][1][(size_t)tid * 8]);
        async_load16(gA,            &As[0][0][(size_t)tid * 8]);
        async_load16(gA + gH1,      &As[0][1][(size_t)tid * 8]);
        async_load16(gB + k1,       &Bs[1][0][(size_t)tid * 8]);
        async_load16(gB + gH1 + k1, &Bs[1][1][(size_t)tid * 8]);
    }
    asm volatile("s_waitcnt vmcnt(2)" ::: "memory");
    __builtin_amdgcn_s_barrier();

    for (int t = 0; t < T; t += 2) {
        GEMM_TILE(t,     0, 1);
        GEMM_TILE(t + 1, 1, 0);
    }
    asm volatile("s_waitcnt vmcnt(0)" ::: "memory");

    const float tscale = scale_from_partials(partials, invCount);

    // C/D layout: col = lane&15, row = quad*4 + reg
    #pragma unroll
    for (int mt = 0; mt < 8; ++mt) {
        #pragma unroll
        for (int nt = 0; nt < 4; ++nt) {
            #pragma unroll
            for (int r = 0; r < 4; ++r) {
                int row = mBase + wr * 128 + mt * 16 + quad * 4 + r;
                int col = nBase + wc * 64 + nt * 16 + lm;
                C[(size_t)row * N + col] = tscale * acc[mt][nt][r];
            }
        }
    }
}

// ---- fallback (ws too small / odd shape): fp32 tiled GEMM ------------------

__global__ void gemm_fallback(const float* __restrict__ x, const float* __restrict__ w,
                              float* __restrict__ out, const float* __restrict__ partials,
                              int N, int K, float invCount)
{
    __shared__ float xs[16][17];
    __shared__ float qs[16][17];
    int tx = threadIdx.x & 15;
    int ty = threadIdx.x >> 4;
    int row = blockIdx.y * 16 + ty;
    int col = blockIdx.x * 16 + tx;
    float acc = 0.0f;
    for (int k0 = 0; k0 < K; k0 += 16) {
        xs[ty][tx] = x[(size_t)row * K + k0 + tx];
        float wv = w[(size_t)(blockIdx.x * 16 + ty) * K + k0 + tx];
        qs[ty][tx] = (wv > 0.5f) ? 1.0f : ((wv < -0.5f) ? -1.0f : 0.0f);
        __syncthreads();
        #pragma unroll
        for (int j = 0; j < 16; ++j) acc += xs[ty][j] * qs[tx][j];
        __syncthreads();
    }
    float tscale = scale_from_partials(partials, invCount);
    out[(size_t)row * N + col] = tscale * acc;
}

__global__ __launch_bounds__(256) void absmean_only(
    const float* __restrict__ w, float* __restrict__ partials, int n4)
{
    int tid = blockIdx.x * blockDim.x + threadIdx.x;
    int stride = gridDim.x * blockDim.x;
    float s = 0.0f;
    for (int i = tid; i < n4; i += stride) {
        float4 v = ((const float4*)w)[i];
        s += fabsf(v.x) + fabsf(v.y) + fabsf(v.z) + fabsf(v.w);
    }
    #pragma unroll
    for (int off = 32; off > 0; off >>= 1) s += __shfl_down(s, off, 64);
    __shared__ float psum[4];
    int lane = threadIdx.x & 63, wid = threadIdx.x >> 6;
    if (lane == 0) psum[wid] = s;
    __syncthreads();
    if (threadIdx.x == 0)
        partials[blockIdx.x] = psum[0] + psum[1] + psum[2] + psum[3];
}

// ---------------------------------------------------------------------------

extern "C" void kernel_launch(void* const* d_in, const int* in_sizes, int n_in,
                              void* d_out, int out_size, void* d_ws, size_t ws_size,
                              hipStream_t stream) {
    const float* x = (const float*)d_in[0];
    const float* w = (const float*)d_in[1];
    float* out = (float*)d_out;

    const int K = 4096;
    const int M = in_sizes[0] / K;       // 8192
    const int N = in_sizes[1] / K;       // 4096
    const float invCount = 1.0f / (float)(in_sizes[1]);

    float* partials = (float*)d_ws;                       // NPART floats = 16 KB
    const size_t base = NPART * sizeof(float);
    const size_t need = base + (size_t)M * K * 2 + (size_t)N * K * 2;

    const bool shapes_ok = (M % BM == 0) && (N % BN == 0) && (K % (2 * BK) == 0);

    if (ws_size >= need && shapes_ok) {
        __bf16* xb = (__bf16*)((char*)d_ws + base);
        __bf16* qb = (__bf16*)((char*)d_ws + base + (size_t)M * K * 2);

        int xn4 = (M * K) / 4;
        int wn4 = (N * K) / 4;
        quant_w_bf16<<<NPART, 256, 0, stream>>>(w, (ushort4*)qb, partials, wn4);
        conv_x_bf16<<<(xn4 + 255) / 256, 256, 0, stream>>>(x, (ushort4*)xb, xn4);

        dim3 grid(N / BN, M / BM);
        gemm_bt<<<grid, 512, 0, stream>>>(xb, qb, out, partials, N, K, invCount);
    } else {
        absmean_only<<<NPART, 256, 0, stream>>>(w, partials, in_sizes[1] / 4);
        dim3 grid(N / 16, M / 16);
        gemm_fallback<<<grid, 256, 0, stream>>>(x, w, out, partials, N, K, invCount);
    }
}

// Round 2
// 459.042 us; speedup vs baseline: 1.2458x; 1.1421x over previous
//
#include <hip/hip_runtime.h>
#include <hip/hip_bf16.h>
#include <stdint.h>

// ---------------------------------------------------------------------------
// TernaryLinear: out[b,s,o] = t * sum_i x[b,s,i] * q[o,i]
//   q = ternary(weight) in {-1,0,+1}; t = clip(round(1/(mean|W|+eps)),-1,1)
// R3: BK=64, 128KB double-buffered LDS (1 WG/CU), 4-phase/tile schedule
//     (16 MFMA per barrier), R1-proven cc^(row&7) swizzle on 128B rows
//     (zero-conflict by construction), counted vmcnt(4) once per tile,
//     setprio around MFMA, XCD swizzle. b0/b1 register reuse across phases.
// ---------------------------------------------------------------------------

typedef __bf16 bf16x8 __attribute__((ext_vector_type(8)));
typedef float  f32x4  __attribute__((ext_vector_type(4)));

#define EPS 1e-7f
#define NPART 4096   // partial-sum slots (quant kernel grid size)

__device__ __forceinline__ void async_load16(const void* g, void* l) {
    __builtin_amdgcn_global_load_lds(
        (__attribute__((address_space(1))) void*)(const_cast<void*>(g)),
        (__attribute__((address_space(3))) void*)l,
        16, 0, 0);
}

__device__ __forceinline__ unsigned short f2bf_rne(float f) {
    unsigned u = __float_as_uint(f);
    unsigned r = (u + 0x7fffu + ((u >> 16) & 1u)) >> 16;
    return (unsigned short)r;
}

// Reduce NPART partials -> scalar scale t. Redundant per-wave (L2-hot 16KB).
__device__ __forceinline__ float scale_from_partials(const float* __restrict__ partials,
                                                     float invCount) {
    const int lane = threadIdx.x & 63;
    const float4* p4 = (const float4*)partials;   // NPART/4 = 1024 entries
    float s = 0.0f;
    #pragma unroll
    for (int j = 0; j < NPART / 4 / 64; ++j) {
        float4 v = p4[lane + 64 * j];
        s += v.x + v.y + v.z + v.w;
    }
    #pragma unroll
    for (int off = 32; off > 0; off >>= 1) s += __shfl_down(s, off, 64);
    s = __shfl(s, 0, 64);
    float mean = s * invCount;
    float gp = 1.0f / (mean + EPS);
    return fminf(fmaxf(rintf(gp), -1.0f), 1.0f);  // rintf = RNE = half-to-even
}

// ---- fused quantize W -> bf16 ternary + per-block |W| partial sums --------

__device__ __forceinline__ unsigned short tern_bf16(float w) {
    // +1 -> 0x3F80, -1 -> 0xBF80, 0 -> 0x0000 (exact bf16 bit patterns)
    return (w > 0.5f) ? (unsigned short)0x3F80u
         : ((w < -0.5f) ? (unsigned short)0xBF80u : (unsigned short)0u);
}

__global__ __launch_bounds__(256) void quant_w_bf16(
    const float* __restrict__ in, ushort4* __restrict__ out,
    float* __restrict__ partials, int n4)
{
    int tid = blockIdx.x * blockDim.x + threadIdx.x;
    int stride = gridDim.x * blockDim.x;
    float s = 0.0f;
    for (int i = tid; i < n4; i += stride) {
        float4 v = ((const float4*)in)[i];
        s += fabsf(v.x) + fabsf(v.y) + fabsf(v.z) + fabsf(v.w);
        ushort4 r;
        r.x = tern_bf16(v.x); r.y = tern_bf16(v.y);
        r.z = tern_bf16(v.z); r.w = tern_bf16(v.w);
        out[i] = r;
    }
    #pragma unroll
    for (int off = 32; off > 0; off >>= 1) s += __shfl_down(s, off, 64);
    __shared__ float psum[4];
    int lane = threadIdx.x & 63, wid = threadIdx.x >> 6;
    if (lane == 0) psum[wid] = s;
    __syncthreads();
    if (threadIdx.x == 0)
        partials[blockIdx.x] = psum[0] + psum[1] + psum[2] + psum[3];
}

// ---- x -> bf16 -------------------------------------------------------------

__global__ __launch_bounds__(256) void conv_x_bf16(
    const float* __restrict__ in, ushort4* __restrict__ out, int n4)
{
    int i = blockIdx.x * blockDim.x + threadIdx.x;
    if (i < n4) {
        float4 v = ((const float4*)in)[i];
        ushort4 r;
        r.x = f2bf_rne(v.x); r.y = f2bf_rne(v.y);
        r.z = f2bf_rne(v.z); r.w = f2bf_rne(v.w);
        out[i] = r;
    }
}

// ---- bf16 MFMA GEMM, 256x256 tile, BK=64, 4-phase counted-vmcnt pipeline --
//
// 8 waves (wr = row-half, wc = col-quarter). Per wave: 128x64 out = 8x4
// 16x16 frags, acc[8][4]. LDS (dynamic, 128KB): As/Bs [2 dbuf][2 half]
// [128 rows][64 bf16] (128B rows). Swizzle: chunk (row, sc) holds logical
// 16B chunk cc = sc ^ (row&7)  -> every aligned 8-lane group of a
// ds_read_b128 covers all 8 bank-groups (R1-measured: 0 conflicts).
// global_load_lds dest stays linear; source address pre-swizzled.
//
// Per tile tau (buf c = tau&1), quadrant order (qm,qn)=(0,0),(0,1),(1,1),(1,0):
//  P1: read A qm0 (8 b128) + B qn0 -> b0 (4) | stage A(tau+1)h0 -> buf c^1
//      | BAR-less: lgkm(0) SBAR0 setprio MFMA16(0,0) | BAR
//  P2: read B qn1 -> b1 (4) | stage A(tau+1)h1 | lgkm(0) MFMA16(0,1) | BAR
//  P3: read A qm1 (8) | stage B(tau+2)h0 -> buf c (B reads done at P2-BAR)
//      | lgkm(0) MFMA16(1,1) | BAR
//  P4: stage B(tau+2)h1 | MFMA16(1,0) (regs only) | vmcnt(4) | BAR
// vmcnt(4): leaves B(tau+2)'s 4 loads in flight across the tile boundary;
// guarantees A(tau+1) (issued P1/P2) + B(tau+1) (issued prev tile P3/P4)
// landed. Never drains to 0 in the loop. Tail tiles re-stage clamped
// sources (never read); final vmcnt(0) drains before epilogue.

#define BM 256
#define BN 256
#define BK 64

#define LDSA(buf, h) (ldsbuf + ((buf) * 2 + (h)) * 8192)
#define LDSB(buf, h) (ldsbuf + 32768 + ((buf) * 2 + (h)) * 8192)

// stage one 128-row half-tile (16KB): 2 global_load_lds per thread
#define STAGE(dst, p, tt, h)                                                   \
  {                                                                            \
    __bf16* d_ = (dst);                                                        \
    const __bf16* s_ = (p) + (size_t)(tt) * BK + (size_t)(h) * 128 * K;        \
    async_load16(s_,                 d_ + (size_t)tid * 8);                    \
    async_load16(s_ + (size_t)64 * K, d_ + 4096 + (size_t)tid * 8);            \
  }

#define READ_A(buf, qm)                                                        \
  _Pragma("unroll")                                                            \
  for (int i = 0; i < 4; ++i) {                                                \
    const __bf16* r_ = LDSA(buf, wr) + ((qm) * 64 + i * 16 + lm) * 64;         \
    areg[i][0] = *(const bf16x8*)(r_ + sl0);                                   \
    areg[i][1] = *(const bf16x8*)(r_ + sl1);                                   \
  }

#define READ_B(buf, qn, dst)                                                   \
  _Pragma("unroll")                                                            \
  for (int j = 0; j < 2; ++j) {                                                \
    const __bf16* r_ = LDSB(buf, wh) + (wb + (qn) * 32 + j * 16 + lm) * 64;    \
    dst[j][0] = *(const bf16x8*)(r_ + sl0);                                    \
    dst[j][1] = *(const bf16x8*)(r_ + sl1);                                    \
  }

#define MFMA16(qm, qn, breg)                                                   \
  __builtin_amdgcn_s_setprio(1);                                               \
  _Pragma("unroll")                                                            \
  for (int i = 0; i < 4; ++i) {                                                \
    _Pragma("unroll")                                                          \
    for (int j = 0; j < 2; ++j) {                                              \
      acc[(qm) * 4 + i][(qn) * 2 + j] = __builtin_amdgcn_mfma_f32_16x16x32_bf16( \
          areg[i][0], breg[j][0], acc[(qm) * 4 + i][(qn) * 2 + j], 0, 0, 0);   \
      acc[(qm) * 4 + i][(qn) * 2 + j] = __builtin_amdgcn_mfma_f32_16x16x32_bf16( \
          areg[i][1], breg[j][1], acc[(qm) * 4 + i][(qn) * 2 + j], 0, 0, 0);   \
    }                                                                          \
  }                                                                            \
  __builtin_amdgcn_s_setprio(0);

#define LGKM0                                                                  \
  asm volatile("s_waitcnt lgkmcnt(0)" ::: "memory");                           \
  __builtin_amdgcn_sched_barrier(0);

#define TILE(tt, CUR, NXT)                                                     \
  {                                                                            \
    const int tA = ((tt) + 1 < T) ? ((tt) + 1) : (T - 1);                      \
    const int tB = ((tt) + 2 < T) ? ((tt) + 2) : (T - 1);                      \
    bf16x8 areg[4][2], b0[2][2], b1[2][2];                                     \
    /* P1 */                                                                   \
    READ_A(CUR, 0);                                                            \
    READ_B(CUR, 0, b0);                                                        \
    STAGE(LDSA(NXT, 0), pA, tA, 0);                                            \
    LGKM0;                                                                     \
    MFMA16(0, 0, b0);                                                          \
    __builtin_amdgcn_s_barrier();                                              \
    /* P2 */                                                                   \
    READ_B(CUR, 1, b1);                                                        \
    STAGE(LDSA(NXT, 1), pA, tA, 1);                                            \
    LGKM0;                                                                     \
    MFMA16(0, 1, b1);                                                          \
    __builtin_amdgcn_s_barrier();                                              \
    /* P3 */                                                                   \
    READ_A(CUR, 1);                                                            \
    STAGE(LDSB(CUR, 0), pB, tB, 0);                                            \
    LGKM0;                                                                     \
    MFMA16(1, 1, b1);                                                          \
    __builtin_amdgcn_s_barrier();                                              \
    /* P4 (regs only) */                                                       \
    STAGE(LDSB(CUR, 1), pB, tB, 1);                                            \
    MFMA16(1, 0, b0);                                                          \
    asm volatile("s_waitcnt vmcnt(4)" ::: "memory");                           \
    __builtin_amdgcn_s_barrier();                                              \
  }

__global__ __launch_bounds__(512, 2) void gemm_bt(
    const __bf16* __restrict__ A,   // [M,K] row-major bf16
    const __bf16* __restrict__ B,   // [N,K] row-major bf16 (ternary)
    float* __restrict__ C,          // [M,N] row-major fp32
    const float* __restrict__ partials,
    int N, int K, float invCount)
{
    extern __shared__ __bf16 ldsbuf[];   // 131072 B

    const int tid  = threadIdx.x;
    const int lane = tid & 63;
    const int wid  = tid >> 6;
    const int wr   = wid >> 2;        // A half this wave consumes (0,1)
    const int wc   = wid & 3;         // col quarter (0..3)
    const int wh   = wc >> 1;         // B half this wave consumes
    const int wb   = (wc & 1) * 64;   // row offset inside that B half
    const int lm   = lane & 15;
    const int quad = lane >> 4;

    // read-side swizzled k-slot offsets (elements): cc = ks*4+quad, sc = cc^(lm&7)
    const int sl0 = ((0 * 4 + quad) ^ (lm & 7)) * 8;
    const int sl1 = ((1 * 4 + quad) ^ (lm & 7)) * 8;

    // T1: XCD-aware swizzle of linear workgroup id (nwg % 8 == 0 here)
    const int gx  = gridDim.x;
    const int nwg = gx * gridDim.y;
    int wg = blockIdx.y * gx + blockIdx.x;
    wg = (wg & 7) * (nwg >> 3) + (wg >> 3);
    const int mBase = (wg / gx) * BM;
    const int nBase = (wg % gx) * BN;

    // staging geometry: thread covers chunks tid (row0, sc) and 512+tid
    // (row0+64, same sc). Source chunk cc = sc ^ (row&7); 64 = 0 mod 8 so
    // both loads share cc.
    const int row0 = tid >> 3;
    const int cc0  = (tid & 7) ^ (row0 & 7);
    const __bf16* pA = A + (size_t)(mBase + row0) * K + cc0 * 8;
    const __bf16* pB = B + (size_t)(nBase + row0) * K + cc0 * 8;

    const int T = K / BK;
    f32x4 acc[8][4] = {};

    // prologue: A0 h0,h1; B0 h0,h1; B1 h0,h1 (12 loads); leave B1 (4) in flight
    STAGE(LDSA(0, 0), pA, 0, 0);
    STAGE(LDSA(0, 1), pA, 0, 1);
    STAGE(LDSB(0, 0), pB, 0, 0);
    STAGE(LDSB(0, 1), pB, 0, 1);
    {
        const int t1 = (T > 1) ? 1 : 0;
        STAGE(LDSB(1, 0), pB, t1, 0);
        STAGE(LDSB(1, 1), pB, t1, 1);
    }
    asm volatile("s_waitcnt vmcnt(4)" ::: "memory");
    __builtin_amdgcn_s_barrier();

    for (int t = 0; t < T; t += 2) {
        TILE(t,     0, 1);
        TILE(t + 1, 1, 0);
    }
    asm volatile("s_waitcnt vmcnt(0)" ::: "memory");
    __builtin_amdgcn_s_barrier();

    const float tscale = scale_from_partials(partials, invCount);

    // C/D layout: col = lane&15, row = quad*4 + reg
    #pragma unroll
    for (int mt = 0; mt < 8; ++mt) {
        #pragma unroll
        for (int nt = 0; nt < 4; ++nt) {
            #pragma unroll
            for (int r = 0; r < 4; ++r) {
                int row = mBase + wr * 128 + mt * 16 + quad * 4 + r;
                int col = nBase + wc * 64 + nt * 16 + lm;
                C[(size_t)row * N + col] = tscale * acc[mt][nt][r];
            }
        }
    }
}

// ---- fallback (ws too small / odd shape / no big-LDS): fp32 tiled GEMM ----

__global__ void gemm_fallback(const float* __restrict__ x, const float* __restrict__ w,
                              float* __restrict__ out, const float* __restrict__ partials,
                              int N, int K, float invCount)
{
    __shared__ float xs[16][17];
    __shared__ float qs[16][17];
    int tx = threadIdx.x & 15;
    int ty = threadIdx.x >> 4;
    int row = blockIdx.y * 16 + ty;
    int col = blockIdx.x * 16 + tx;
    float acc = 0.0f;
    for (int k0 = 0; k0 < K; k0 += 16) {
        xs[ty][tx] = x[(size_t)row * K + k0 + tx];
        float wv = w[(size_t)(blockIdx.x * 16 + ty) * K + k0 + tx];
        qs[ty][tx] = (wv > 0.5f) ? 1.0f : ((wv < -0.5f) ? -1.0f : 0.0f);
        __syncthreads();
        #pragma unroll
        for (int j = 0; j < 16; ++j) acc += xs[ty][j] * qs[tx][j];
        __syncthreads();
    }
    float tscale = scale_from_partials(partials, invCount);
    out[(size_t)row * N + col] = tscale * acc;
}

__global__ __launch_bounds__(256) void absmean_only(
    const float* __restrict__ w, float* __restrict__ partials, int n4)
{
    int tid = blockIdx.x * blockDim.x + threadIdx.x;
    int stride = gridDim.x * blockDim.x;
    float s = 0.0f;
    for (int i = tid; i < n4; i += stride) {
        float4 v = ((const float4*)w)[i];
        s += fabsf(v.x) + fabsf(v.y) + fabsf(v.z) + fabsf(v.w);
    }
    #pragma unroll
    for (int off = 32; off > 0; off >>= 1) s += __shfl_down(s, off, 64);
    __shared__ float psum[4];
    int lane = threadIdx.x & 63, wid = threadIdx.x >> 6;
    if (lane == 0) psum[wid] = s;
    __syncthreads();
    if (threadIdx.x == 0)
        partials[blockIdx.x] = psum[0] + psum[1] + psum[2] + psum[3];
}

// ---------------------------------------------------------------------------

extern "C" void kernel_launch(void* const* d_in, const int* in_sizes, int n_in,
                              void* d_out, int out_size, void* d_ws, size_t ws_size,
                              hipStream_t stream) {
    const float* x = (const float*)d_in[0];
    const float* w = (const float*)d_in[1];
    float* out = (float*)d_out;

    const int K = 4096;
    const int M = in_sizes[0] / K;       // 8192
    const int N = in_sizes[1] / K;       // 4096
    const float invCount = 1.0f / (float)(in_sizes[1]);

    float* partials = (float*)d_ws;                       // NPART floats = 16 KB
    const size_t base = NPART * sizeof(float);
    const size_t need = base + (size_t)M * K * 2 + (size_t)N * K * 2;

    // one-time: allow 128KB dynamic LDS for gemm_bt
    static int big_lds_ok = -1;
    if (big_lds_ok < 0) {
        hipError_t e = hipFuncSetAttribute((const void*)gemm_bt,
                                           hipFuncAttributeMaxDynamicSharedMemorySize,
                                           131072);
        big_lds_ok = (e == hipSuccess) ? 1 : 0;
    }

    const bool shapes_ok = (M % BM == 0) && (N % BN == 0) && (K % (2 * BK) == 0);

    if (ws_size >= need && shapes_ok && big_lds_ok == 1) {
        __bf16* xb = (__bf16*)((char*)d_ws + base);
        __bf16* qb = (__bf16*)((char*)d_ws + base + (size_t)M * K * 2);

        int xn4 = (M * K) / 4;
        int wn4 = (N * K) / 4;
        quant_w_bf16<<<NPART, 256, 0, stream>>>(w, (ushort4*)qb, partials, wn4);
        conv_x_bf16<<<(xn4 + 255) / 256, 256, 0, stream>>>(x, (ushort4*)xb, xn4);

        dim3 grid(N / BN, M / BM);
        gemm_bt<<<grid, 512, 131072, stream>>>(xb, qb, out, partials, N, K, invCount);
    } else {
        absmean_only<<<NPART, 256, 0, stream>>>(w, partials, in_sizes[1] / 4);
        dim3 grid(N / 16, M / 16);
        gemm_fallback<<<grid, 256, 0, stream>>>(x, w, out, partials, N, K, invCount);
    }
}